// Round 3
// baseline (516.426 us; speedup 1.0000x reference)
//
#include <hip/hip_runtime.h>
#include <math.h>

// Problem constants (fixed by the reference):
#define GP 8
#define GB 256
#define GN 512
#define GK 64

__device__ __forceinline__ float dot4(const float4 a, const float4 b) {
    return (a.x * b.x + a.y * b.y) + (a.z * b.z + a.w * b.w);
}

__device__ __forceinline__ float red64(float v) {
    v += __shfl_xor(v, 1);
    v += __shfl_xor(v, 2);
    v += __shfl_xor(v, 4);
    v += __shfl_xor(v, 8);
    v += __shfl_xor(v, 16);
    v += __shfl_xor(v, 32);
    return v;
}

// ---------------------------------------------------------------------------
// Kernel A: streams WR[p,b] (128 KB/block). Computes
//   WRx[p,b,k] = WR[p,b,k,:]·v_tm1[b,:]   and   Wx[p,b,k] = WR[p,b,k,:]·v_t[b,:]
// into d_ws, plus the dWR output (v_tm1 * mask/n).
// NO LDS, NO __syncthreads — v vectors live in registers; loads pipelined
// 8-deep per lane so the CU never drains its memory queue.
// ---------------------------------------------------------------------------
__global__ __launch_bounds__(256, 4) void ghu_phase1(
    const float* __restrict__ WR,
    const float* __restrict__ v_tm1,
    const float* __restrict__ v_t,
    const int*   __restrict__ pc_mask,
    float* __restrict__ out,
    float* __restrict__ ws,
    float inv_n)
{
    const int b    = blockIdx.x;
    const int p    = blockIdx.y;
    const int tid  = threadIdx.x;
    const int wave = tid >> 6;
    const int lane = tid & 63;

    // v slices register-resident (coalesced, L3-hot)
    const float4* vu4 = (const float4*)(v_tm1 + b * GN);
    const float4* vt4 = (const float4*)(v_t   + b * GN);
    const float4 u0 = vu4[lane], u1 = vu4[lane + 64];
    const float4 t0 = vt4[lane], t1 = vt4[lane + 64];

    const float4* WR4 = (const float4*)(WR + (size_t)(p * GB + b) * (GK * GN));
    const int k0 = wave * 16;   // this wave owns rows k0..k0+15

    float* gWRx = ws + (size_t)(p * GB + b) * GK;
    float* gWx  = ws + (size_t)GP * GB * GK + (size_t)(p * GB + b) * GK;

    // Ping-pong register buffers: 4 rows (8 wave-contiguous 1KB loads) per batch
    float4 Lb[2][4], Hb[2][4];
    #pragma unroll
    for (int r = 0; r < 4; ++r) {
        Lb[0][r] = WR4[(k0 + r) * 128 + lane];
        Hb[0][r] = WR4[(k0 + r) * 128 + 64 + lane];
    }

    #pragma unroll
    for (int batch = 0; batch < 4; ++batch) {
        const int cur = batch & 1, nxt = cur ^ 1;
        if (batch < 3) {  // issue next batch's 8 loads before touching current data
            #pragma unroll
            for (int r = 0; r < 4; ++r) {
                const int k = k0 + (batch + 1) * 4 + r;
                Lb[nxt][r] = WR4[k * 128 + lane];
                Hb[nxt][r] = WR4[k * 128 + 64 + lane];
            }
        }
        float wrx[4], wx[4];
        #pragma unroll
        for (int r = 0; r < 4; ++r) {
            wrx[r] = dot4(Lb[cur][r], u0) + dot4(Hb[cur][r], u1);
            wx[r]  = dot4(Lb[cur][r], t0) + dot4(Hb[cur][r], t1);
        }
        // 8 independent 6-step butterflies — interleaved by the scheduler
        #pragma unroll
        for (int r = 0; r < 4; ++r) { wrx[r] = red64(wrx[r]); wx[r] = red64(wx[r]); }
        if (lane == 0) {
            *(float4*)(gWRx + k0 + batch * 4) = make_float4(wrx[0], wrx[1], wrx[2], wrx[3]);
            *(float4*)(gWx  + k0 + batch * 4) = make_float4(wx[0],  wx[1],  wx[2],  wx[3]);
        }
    }

    // dWR epilogue: dWR[p,b,0,:] = v_tm1[b,:] * mask/n  (coalesced)
    const float sc = (float)pc_mask[b * GP + p] * inv_n;
    float* dWR_out = out + (size_t)GB * GN + (size_t)GP * GB * GN
                         + (size_t)(p * GB + b) * GN;
    dWR_out[tid]       = v_tm1[b * GN + tid]       * sc;
    dWR_out[tid + 256] = v_tm1[b * GN + tid + 256] * sc;
}

// ---------------------------------------------------------------------------
// Kernel B: streams WL[p,b] (128 KB/block). Computes
//   WLWRx[n] = WL[p,b,n,:]·WRx  -> dWL = (g*v_t - WLWRx)*mask
//   v_next[n] = tanh(WL[p,b,n,:]·Wx)   when p == ac_idx[b]
// 16 lanes per row (K=64 = 16 f4) -> each wave-load covers 4 consecutive rows
// fully contiguous (1 KB); only 4 shuffle steps per reduction. No LDS/barrier.
// ---------------------------------------------------------------------------
__global__ __launch_bounds__(256, 4) void ghu_phase2(
    const float* __restrict__ WL,
    const float* __restrict__ v_t,
    const int*   __restrict__ ac_idx,
    const int*   __restrict__ pc_mask,
    float* __restrict__ out,
    const float* __restrict__ ws,
    float g)
{
    const int b      = blockIdx.x;
    const int p      = blockIdx.y;
    const int tid    = threadIdx.x;
    const int wave   = tid >> 6;
    const int lane   = tid & 63;
    const int sub    = lane & 15;   // f4-chunk of K owned by this lane
    const int rowoff = lane >> 4;   // which of the 4 rows in this wave-load

    // Per-lane WRx/Wx fragments (16 f4 cover K=64), L2/L3-hot from kernel A
    const float4 wr4 = ((const float4*)(ws + (size_t)(p * GB + b) * GK))[sub];
    const float4 wx4 = ((const float4*)(ws + (size_t)GP * GB * GK
                                           + (size_t)(p * GB + b) * GK))[sub];

    const bool  sel   = (ac_idx[b] == p);              // block-uniform
    const float maskv = (float)pc_mask[b * GP + p];

    const float4* WL4 = (const float4*)(WL + (size_t)(p * GB + b) * (GN * GK));

    // iteration t: rows n0..n0+3 with n0 = 16*t + 4*wave ; 4-deep pipeline
    float4 buf[4];
    #pragma unroll
    for (int t = 0; t < 4; ++t)
        buf[t] = WL4[(16 * t + 4 * wave + rowoff) * 16 + sub];

    float* dWL_out = out + (size_t)GB * GN + (size_t)(p * GB + b) * GN;
    const float* vtb = v_t + b * GN;

    #pragma unroll
    for (int t = 0; t < 32; ++t) {
        const float4 cur = buf[t & 3];
        if (t + 4 < 32)
            buf[t & 3] = WL4[(16 * (t + 4) + 4 * wave + rowoff) * 16 + sub];

        float d = dot4(cur, wr4);
        d += __shfl_xor(d, 1);
        d += __shfl_xor(d, 2);
        d += __shfl_xor(d, 4);
        d += __shfl_xor(d, 8);

        float d2 = 0.f;
        if (sel) {
            d2 = dot4(cur, wx4);
            d2 += __shfl_xor(d2, 1);
            d2 += __shfl_xor(d2, 2);
            d2 += __shfl_xor(d2, 4);
            d2 += __shfl_xor(d2, 8);
        }
        if (sub == 0) {
            const int n = 16 * t + 4 * wave + rowoff;
            dWL_out[n] = (g * vtb[n] - d) * maskv;
            if (sel) out[b * GN + n] = tanhf(d2);
        }
    }
}

extern "C" void kernel_launch(void* const* d_in, const int* in_sizes, int n_in,
                              void* d_out, int out_size, void* d_ws, size_t ws_size,
                              hipStream_t stream) {
    const float* WL     = (const float*)d_in[0];
    const float* WR     = (const float*)d_in[1];
    const float* v_tm1  = (const float*)d_in[2];
    const float* v_t    = (const float*)d_in[3];
    const int*   ac_idx = (const int*)d_in[4];
    const int*   pc_msk = (const int*)d_in[5];
    float* out = (float*)d_out;
    float* ws  = (float*)d_ws;   // uses 2*P*B*K*4 = 1 MB

    const double RHO = 0.999;
    const float g     = (float)(0.5 * (log(1.0 + RHO) - log(1.0 - RHO)) / RHO);
    const float inv_n = (float)(1.0 / ((double)GN * RHO * RHO));

    dim3 grid(GB, GP);
    ghu_phase1<<<grid, 256, 0, stream>>>(WR, v_tm1, v_t, pc_msk, out, ws, inv_n);
    ghu_phase2<<<grid, 256, 0, stream>>>(WL, v_t, ac_idx, pc_msk, out, ws, g);
}